// Round 1
// baseline (1463.158 us; speedup 1.0000x reference)
//
#include <hip/hip_runtime.h>

typedef __bf16 bf16x8 __attribute__((ext_vector_type(8)));
typedef unsigned short us8 __attribute__((ext_vector_type(8)));
typedef float f32x4 __attribute__((ext_vector_type(4)));

#define NROW 32      // rows per workgroup
#define A_STR 136    // ushort stride per A row (128 + 8 pad -> 272B, breaks bank alignment)
#define G_STR 516    // float stride per gate row (breaks bank alignment)
#define NSTEP 119

__device__ __forceinline__ unsigned short f2bf(float f){
  unsigned int x = __builtin_bit_cast(unsigned int, f);
  x += 0x7fffu + ((x >> 16) & 1u);          // RNE
  return (unsigned short)(x >> 16);
}
__device__ __forceinline__ float sigm(float x){ return 1.0f/(1.0f + __expf(-x)); }
__device__ __forceinline__ float tanh_(float x){ float e = __expf(2.0f*x); return 1.0f - 2.0f/(e + 1.0f); }

__device__ __forceinline__ f32x4 MFMA(us8 a, us8 b, f32x4 c){
  return __builtin_amdgcn_mfma_f32_16x16x32_bf16(
      __builtin_bit_cast(bf16x8, a), __builtin_bit_cast(bf16x8, b), c, 0, 0, 0);
}

struct SharedMem {
  unsigned short A0[NROW*A_STR];   // h0 state, bf16 (MFMA A operand)
  unsigned short A1[NROW*A_STR];   // h1 state, bf16
  float g[NROW*G_STR];             // gate exchange buffer, f32
  float rowsc[2][NROW][8];         // per-step row scalars: tgt, cov0..3 (double buffered)
  float xu[512][2];                // u[n], v[n]
  float red[NROW][16][2];          // head partial sums
  float we_s[64];
  float be_s[64];
};

__global__ __launch_bounds__(512, 1) void deepar_kernel(
    const float* __restrict__ hist, const float* __restrict__ fut,
    const float* __restrict__ We,   const float* __restrict__ be,
    const float* __restrict__ Wih0, const float* __restrict__ Whh0,
    const float* __restrict__ bih0, const float* __restrict__ bhh0,
    const float* __restrict__ Wih1, const float* __restrict__ Whh1,
    const float* __restrict__ bih1, const float* __restrict__ bhh1,
    const float* __restrict__ Wh,   const float* __restrict__ bh,
    float* __restrict__ out)
{
  __shared__ SharedMem S;
  const int tid = threadIdx.x;
  const int wg  = blockIdx.x;
  const int b   = wg / 10;
  const int n0  = (wg % 10) * NROW;
  const int w   = tid >> 6;        // wave 0..7
  const int l   = tid & 63;
  const int gq  = l >> 4;          // k-group 0..3 within wave
  const int r   = l & 15;
  const int cw  = w * 64;          // gate-col base of this wave
  const int rown = tid >> 4;       // owned state row 0..31
  const int cg   = tid & 15;       // owned col-group (8 h-cols)
  const int hc0  = cg * 8;

  // ---------------- prologue ----------------
  // zero h state buffers
  {
    us8 z = (us8)(unsigned short)0;
    for (int i = tid; i < NROW*A_STR/8; i += 512){
      ((us8*)S.A0)[i] = z;
      ((us8*)S.A1)[i] = z;
    }
  }
  if (tid < 64)       S.we_s[tid]      = We[tid];
  else if (tid < 128) S.be_s[tid - 64] = be[tid - 64];
  __syncthreads();

  // u[n] = Wih0[n,:64]@We ; v[n] = Wih0[n,:64]@be + bih0[n] + bhh0[n]
  {
    const float* wr = Wih0 + tid * 68;
    float u = 0.f, v = 0.f;
    #pragma unroll 8
    for (int e = 0; e < 64; ++e){
      float wv = wr[e];
      u = fmaf(wv, S.we_s[e], u);
      v = fmaf(wv, S.be_s[e], v);
    }
    v += bih0[tid] + bhh0[tid];
    S.xu[tid][0] = u; S.xu[tid][1] = v;
  }
  // stage row scalars for step 0 (tgt at tau=0, cov at tau=1)
  if (tid < 32){
    int n = n0 + tid;
    S.rowsc[0][tid][0] = hist[((b*96 + 0)*320 + n)*5 + 0];
  } else if (tid < 160){
    int k = tid - 32, row = k >> 2, c = k & 3, n = n0 + row;
    S.rowsc[0][row][1 + c] = hist[((b*96 + 1)*320 + n)*5 + 1 + c];
  }
  __syncthreads();

  // per-lane constants
  float uc[4], vc[4], Wc[4][4], b1c[4];
  #pragma unroll
  for (int nt = 0; nt < 4; ++nt){
    int n = cw + nt*16 + r;
    uc[nt] = S.xu[n][0];
    vc[nt] = S.xu[n][1];
    f32x4 wc4 = *(const f32x4*)(Wih0 + n*68 + 64);
    Wc[nt][0] = wc4[0]; Wc[nt][1] = wc4[1]; Wc[nt][2] = wc4[2]; Wc[nt][3] = wc4[3];
    b1c[nt] = bih1[n] + bhh1[n];
  }
  // head constants for owned cols
  float whA[8], whB[8];
  {
    f32x4 a0v = *(const f32x4*)(Wh + hc0);
    f32x4 a1v = *(const f32x4*)(Wh + hc0 + 4);
    f32x4 b0v = *(const f32x4*)(Wh + 128 + hc0);
    f32x4 b1v = *(const f32x4*)(Wh + 128 + hc0 + 4);
    whA[0]=a0v[0]; whA[1]=a0v[1]; whA[2]=a0v[2]; whA[3]=a0v[3];
    whA[4]=a1v[0]; whA[5]=a1v[1]; whA[6]=a1v[2]; whA[7]=a1v[3];
    whB[0]=b0v[0]; whB[1]=b0v[1]; whB[2]=b0v[2]; whB[3]=b0v[3];
    whB[4]=b1v[0]; whB[5]=b1v[1]; whB[6]=b1v[2]; whB[7]=b1v[3];
  }
  const float bh0 = bh[0], bh1 = bh[1];

  // register-resident weight fragments: [mat][n-tile][k-block], contiguous-8 k per lane
  us8 WB[3][4][4];
  #pragma unroll
  for (int m = 0; m < 3; ++m){
    const float* base = (m == 0) ? Whh0 : (m == 1) ? Wih1 : Whh1;
    #pragma unroll
    for (int nt = 0; nt < 4; ++nt){
      #pragma unroll
      for (int q = 0; q < 4; ++q){
        const float* p = base + (cw + nt*16 + r)*128 + q*32 + gq*8;
        f32x4 x0 = *(const f32x4*)p;
        f32x4 x1 = *(const f32x4*)(p + 4);
        us8 tt;
        tt[0]=f2bf(x0[0]); tt[1]=f2bf(x0[1]); tt[2]=f2bf(x0[2]); tt[3]=f2bf(x0[3]);
        tt[4]=f2bf(x1[0]); tt[5]=f2bf(x1[1]); tt[6]=f2bf(x1[2]); tt[7]=f2bf(x1[3]);
        WB[m][nt][q] = tt;
      }
    }
  }

  float c0s[8], c1s[8];
  #pragma unroll
  for (int j = 0; j < 8; ++j){ c0s[j] = 0.f; c1s[j] = 0.f; }

  __syncthreads();

  // ---------------- time loop ----------------
  for (int t = 0; t < NSTEP; ++t){
    const int buf = t & 1;
    f32x4 acc[2][4];

    // ---- phase 1: layer-0 gates = h0 @ Whh0^T + (u*tgt + v + Wcov@cov)
    #pragma unroll
    for (int rt = 0; rt < 2; ++rt)
      #pragma unroll
      for (int nt = 0; nt < 4; ++nt){ f32x4 z = {0.f,0.f,0.f,0.f}; acc[rt][nt] = z; }

    #pragma unroll
    for (int q = 0; q < 4; ++q){
      us8 a0 = *(const us8*)&S.A0[(r)     *A_STR + q*32 + gq*8];
      us8 a1 = *(const us8*)&S.A0[(16 + r)*A_STR + q*32 + gq*8];
      #pragma unroll
      for (int nt = 0; nt < 4; ++nt){
        acc[0][nt] = MFMA(a0, WB[0][nt][q], acc[0][nt]);
        acc[1][nt] = MFMA(a1, WB[0][nt][q], acc[1][nt]);
      }
    }
    // x-part (exact fp32)
    #pragma unroll
    for (int rt = 0; rt < 2; ++rt){
      #pragma unroll
      for (int j = 0; j < 4; ++j){
        int rowl = rt*16 + gq*4 + j;
        f32x4 sc = *(const f32x4*)&S.rowsc[buf][rowl][0];
        float cv3 = S.rowsc[buf][rowl][4];
        #pragma unroll
        for (int nt = 0; nt < 4; ++nt){
          float xg = fmaf(uc[nt], sc[0], vc[nt]);
          xg = fmaf(Wc[nt][0], sc[1], xg);
          xg = fmaf(Wc[nt][1], sc[2], xg);
          xg = fmaf(Wc[nt][2], sc[3], xg);
          xg = fmaf(Wc[nt][3], cv3,  xg);
          acc[rt][nt][j] += xg;
        }
      }
    }
    #pragma unroll
    for (int rt = 0; rt < 2; ++rt)
      #pragma unroll
      for (int nt = 0; nt < 4; ++nt)
        #pragma unroll
        for (int j = 0; j < 4; ++j)
          S.g[(rt*16 + gq*4 + j)*G_STR + cw + nt*16 + r] = acc[rt][nt][j];
    __syncthreads();   // B1

    // ---- phase 2: layer-0 activations, write h0 (bf16) ----
    {
      const float* gp = &S.g[rown*G_STR + hc0];
      f32x4 gi0 = *(const f32x4*)(gp);       f32x4 gi1 = *(const f32x4*)(gp + 4);
      f32x4 gf0 = *(const f32x4*)(gp + 128); f32x4 gf1 = *(const f32x4*)(gp + 132);
      f32x4 gg0 = *(const f32x4*)(gp + 256); f32x4 gg1 = *(const f32x4*)(gp + 260);
      f32x4 go0 = *(const f32x4*)(gp + 384); f32x4 go1 = *(const f32x4*)(gp + 388);
      float giv[8] = {gi0[0],gi0[1],gi0[2],gi0[3],gi1[0],gi1[1],gi1[2],gi1[3]};
      float gfv[8] = {gf0[0],gf0[1],gf0[2],gf0[3],gf1[0],gf1[1],gf1[2],gf1[3]};
      float ggv[8] = {gg0[0],gg0[1],gg0[2],gg0[3],gg1[0],gg1[1],gg1[2],gg1[3]};
      float gov[8] = {go0[0],go0[1],go0[2],go0[3],go1[0],go1[1],go1[2],go1[3]};
      us8 hv;
      #pragma unroll
      for (int jj = 0; jj < 8; ++jj){
        float isg = sigm(giv[jj]);
        float fsg = sigm(gfv[jj]);
        float gth = tanh_(ggv[jj]);
        float osg = sigm(gov[jj]);
        float c = fmaf(fsg, c0s[jj], isg*gth);
        c0s[jj] = c;
        hv[jj] = f2bf(osg * tanh_(c));
      }
      *(us8*)&S.A0[rown*A_STR + hc0] = hv;
    }
    __syncthreads();   // B2

    // issue next-step row-scalar loads early (latency hides under L1 MFMA)
    float stv = 0.f; float* stp = nullptr;
    if (t + 1 < NSTEP){
      int row = -1, ch = -1, tau = 0;
      if (tid < 32){ row = tid; ch = 0; tau = t + 1; }
      else if (tid < 160){ int k = tid - 32; row = k >> 2; ch = 1 + (k & 3); tau = t + 2; }
      if (ch >= 0){
        int n = n0 + row;
        const float* p = (tau < 96) ? (hist + ((b*96 + tau)*320 + n)*5)
                                    : (fut  + ((b*24 + (tau - 96))*320 + n)*5);
        stv = p[ch];
        stp = &S.rowsc[(t + 1) & 1][row][ch];
      }
    }

    // ---- phase 3: layer-1 gates = h0_new @ Wih1^T + h1 @ Whh1^T + b1 ----
    #pragma unroll
    for (int rt = 0; rt < 2; ++rt)
      #pragma unroll
      for (int nt = 0; nt < 4; ++nt){ f32x4 z = {0.f,0.f,0.f,0.f}; acc[rt][nt] = z; }

    #pragma unroll
    for (int q = 0; q < 4; ++q){
      us8 a0 = *(const us8*)&S.A0[(r)     *A_STR + q*32 + gq*8];
      us8 a1 = *(const us8*)&S.A0[(16 + r)*A_STR + q*32 + gq*8];
      #pragma unroll
      for (int nt = 0; nt < 4; ++nt){
        acc[0][nt] = MFMA(a0, WB[1][nt][q], acc[0][nt]);
        acc[1][nt] = MFMA(a1, WB[1][nt][q], acc[1][nt]);
      }
    }
    #pragma unroll
    for (int q = 0; q < 4; ++q){
      us8 a0 = *(const us8*)&S.A1[(r)     *A_STR + q*32 + gq*8];
      us8 a1 = *(const us8*)&S.A1[(16 + r)*A_STR + q*32 + gq*8];
      #pragma unroll
      for (int nt = 0; nt < 4; ++nt){
        acc[0][nt] = MFMA(a0, WB[2][nt][q], acc[0][nt]);
        acc[1][nt] = MFMA(a1, WB[2][nt][q], acc[1][nt]);
      }
    }
    #pragma unroll
    for (int rt = 0; rt < 2; ++rt)
      #pragma unroll
      for (int nt = 0; nt < 4; ++nt)
        #pragma unroll
        for (int j = 0; j < 4; ++j)
          S.g[(rt*16 + gq*4 + j)*G_STR + cw + nt*16 + r] = acc[rt][nt][j] + b1c[nt];
    if (stp) *stp = stv;
    __syncthreads();   // B3

    // ---- phase 4: layer-1 activations, write h1, head partials ----
    {
      const float* gp = &S.g[rown*G_STR + hc0];
      f32x4 gi0 = *(const f32x4*)(gp);       f32x4 gi1 = *(const f32x4*)(gp + 4);
      f32x4 gf0 = *(const f32x4*)(gp + 128); f32x4 gf1 = *(const f32x4*)(gp + 132);
      f32x4 gg0 = *(const f32x4*)(gp + 256); f32x4 gg1 = *(const f32x4*)(gp + 260);
      f32x4 go0 = *(const f32x4*)(gp + 384); f32x4 go1 = *(const f32x4*)(gp + 388);
      float giv[8] = {gi0[0],gi0[1],gi0[2],gi0[3],gi1[0],gi1[1],gi1[2],gi1[3]};
      float gfv[8] = {gf0[0],gf0[1],gf0[2],gf0[3],gf1[0],gf1[1],gf1[2],gf1[3]};
      float ggv[8] = {gg0[0],gg0[1],gg0[2],gg0[3],gg1[0],gg1[1],gg1[2],gg1[3]};
      float gov[8] = {go0[0],go0[1],go0[2],go0[3],go1[0],go1[1],go1[2],go1[3]};
      us8 hv; float pm = 0.f, ps = 0.f;
      #pragma unroll
      for (int jj = 0; jj < 8; ++jj){
        float isg = sigm(giv[jj]);
        float fsg = sigm(gfv[jj]);
        float gth = tanh_(ggv[jj]);
        float osg = sigm(gov[jj]);
        float c = fmaf(fsg, c1s[jj], isg*gth);
        c1s[jj] = c;
        float h = osg * tanh_(c);
        hv[jj] = f2bf(h);
        float hr = h > 0.f ? h : 0.f;
        pm = fmaf(hr, whA[jj], pm);
        ps = fmaf(hr, whB[jj], ps);
      }
      *(us8*)&S.A1[rown*A_STR + hc0] = hv;
      if (t >= 95){ S.red[rown][cg][0] = pm; S.red[rown][cg][1] = ps; }
    }
    __syncthreads();   // B4

    // head reduce + store (last 24 steps), one wave
    if (t >= 95 && tid < 64){
      int row = tid >> 1, o = tid & 1;
      float s = o ? bh1 : bh0;
      #pragma unroll
      for (int k = 0; k < 16; ++k) s += S.red[row][k][o];
      float val = o ? ((s > 15.f) ? s : __logf(1.0f + __expf(s))) : s;
      out[((b*24 + (t - 95))*320 + (n0 + row))*2 + o] = val;
    }
  }
}

extern "C" void kernel_launch(void* const* d_in, const int* in_sizes, int n_in,
                              void* d_out, int out_size, void* d_ws, size_t ws_size,
                              hipStream_t stream) {
  const float* hist = (const float*)d_in[0];
  const float* fut  = (const float*)d_in[1];
  const float* We   = (const float*)d_in[2];
  const float* be   = (const float*)d_in[3];
  const float* Wih0 = (const float*)d_in[4];
  const float* Whh0 = (const float*)d_in[5];
  const float* bih0 = (const float*)d_in[6];
  const float* bhh0 = (const float*)d_in[7];
  const float* Wih1 = (const float*)d_in[8];
  const float* Whh1 = (const float*)d_in[9];
  const float* bih1 = (const float*)d_in[10];
  const float* bhh1 = (const float*)d_in[11];
  const float* Wh   = (const float*)d_in[12];
  const float* bh   = (const float*)d_in[13];
  float* out = (float*)d_out;

  deepar_kernel<<<dim3(160), dim3(512), 0, stream>>>(
      hist, fut, We, be, Wih0, Whh0, bih0, bhh0,
      Wih1, Whh1, bih1, bhh1, Wh, bh, out);
}

// Round 2
// 1217.910 us; speedup vs baseline: 1.2014x; 1.2014x over previous
//
#include <hip/hip_runtime.h>

typedef __bf16 bf16x8 __attribute__((ext_vector_type(8)));
typedef unsigned short us8 __attribute__((ext_vector_type(8)));
typedef float f32x4 __attribute__((ext_vector_type(4)));

#define NROW 32      // rows per workgroup (160 WGs x 32 = 5120)
#define A_STR 136    // ushort stride per A row: 16B-aligned, 4-dword bank skew
#define NSTEP 119

__device__ __forceinline__ unsigned short f2bf(float f){
  unsigned int x = __builtin_bit_cast(unsigned int, f);
  x += 0x7fffu + ((x >> 16) & 1u);          // RNE
  return (unsigned short)(x >> 16);
}
__device__ __forceinline__ float bf2f(unsigned short s){
  unsigned int x = ((unsigned int)s) << 16;
  return __builtin_bit_cast(float, x);
}
__device__ __forceinline__ float sigm(float x){ return 1.0f/(1.0f + __expf(-x)); }
__device__ __forceinline__ float tanh_(float x){ float e = __expf(2.0f*x); return 1.0f - 2.0f/(e + 1.0f); }

__device__ __forceinline__ f32x4 MFMA(us8 a, us8 b, f32x4 c){
  return __builtin_amdgcn_mfma_f32_16x16x32_bf16(
      __builtin_bit_cast(bf16x8, a), __builtin_bit_cast(bf16x8, b), c, 0, 0, 0);
}

struct SharedMem {
  unsigned short A0[2][NROW*A_STR];   // h0 state, bf16, double buffered
  unsigned short A1[2][NROW*A_STR];   // h1 state, bf16, double buffered
  unsigned short Ax[2][NROW][32];     // x-MFMA A operand: k=0 tgt, 1-4 cov, 5 one, 6.. zero
  unsigned short xw[512*8];           // x-MFMA B operand per gate-col: u,Wc0-3,v,0,0
  float b1[512];                      // bih1+bhh1 per col
  float Wh2f[256];                    // Wh flattened
  float red[NROW][16][2];             // head partial sums
  float we_s[64];
  float be_s[64];
  float bh_s[2];
};

__global__ __launch_bounds__(512, 2) void deepar_kernel(
    const float* __restrict__ hist, const float* __restrict__ fut,
    const float* __restrict__ We,   const float* __restrict__ be,
    const float* __restrict__ Wih0, const float* __restrict__ Whh0,
    const float* __restrict__ bih0, const float* __restrict__ bhh0,
    const float* __restrict__ Wih1, const float* __restrict__ Whh1,
    const float* __restrict__ bih1, const float* __restrict__ bhh1,
    const float* __restrict__ Wh,   const float* __restrict__ bh,
    float* __restrict__ out)
{
  __shared__ SharedMem S;
  const int tid = threadIdx.x;
  const int wg  = blockIdx.x;
  const int b   = wg / 10;
  const int n0  = (wg % 10) * NROW;
  const int w   = tid >> 6;        // wave 0..7
  const int l   = tid & 63;
  const int gq  = l >> 4;          // k-group 0..3
  const int r   = l & 15;          // row/col within 16-tile

  // ---------------- prologue: zero + param staging ----------------
  {
    us8 z = {0,0,0,0,0,0,0,0};
    us8* pA0 = (us8*)&S.A0[0][0];
    us8* pA1 = (us8*)&S.A1[0][0];
    for (int i = tid; i < 2*NROW*A_STR/8; i += 512){ pA0[i] = z; pA1[i] = z; }
    us8* pAx = (us8*)&S.Ax[0][0][0];
    for (int i = tid; i < 2*NROW*32/8; i += 512) pAx[i] = z;
  }
  if (tid < 64)       S.we_s[tid]       = We[tid];
  else if (tid < 128) S.be_s[tid - 64]  = be[tid - 64];
  else if (tid < 384) S.Wh2f[tid - 128] = Wh[tid - 128];
  else if (tid < 386) S.bh_s[tid - 384] = bh[tid - 384];
  __syncthreads();

  // per-col x weights: u = Wih0[:, :64]@We ; v = Wih0[:, :64]@be + bih0 + bhh0
  {
    const float* wr = Wih0 + tid * 68;
    float u = 0.f, v = 0.f;
    #pragma unroll 8
    for (int e = 0; e < 64; ++e){
      float wv = wr[e];
      u = fmaf(wv, S.we_s[e], u);
      v = fmaf(wv, S.be_s[e], v);
    }
    v += bih0[tid] + bhh0[tid];
    unsigned short* xp = &S.xw[tid * 8];
    xp[0] = f2bf(u);
    xp[1] = f2bf(wr[64]); xp[2] = f2bf(wr[65]); xp[3] = f2bf(wr[66]); xp[4] = f2bf(wr[67]);
    xp[5] = f2bf(v);
    xp[6] = 0; xp[7] = 0;
    S.b1[tid] = bih1[tid] + bhh1[tid];
  }
  // Ax constant-one column (k=5), both buffers
  if (tid < 64){ int row = tid >> 1, bsel = tid & 1; S.Ax[bsel][row][5] = 0x3F80; }
  // stage step-0 scalars: tgt tau=0, cov tau=1 -> Ax[0]
  if (tid < 160){
    int srow, sch, tau;
    if (tid < 32){ srow = tid; sch = 0; tau = 0; }
    else { int k = tid - 32; srow = k >> 2; sch = 1 + (k & 3); tau = 1; }
    const float* p = hist + ((b*96 + tau)*320 + n0 + srow)*5;
    S.Ax[0][srow][sch] = f2bf(p[sch]);
  }

  // register-resident recurrent weights: WB[mat][gate][kblock]
  us8 WB[3][4][4];
  #pragma unroll
  for (int m = 0; m < 3; ++m){
    const float* base = (m == 0) ? Whh0 : (m == 1) ? Wih1 : Whh1;
    #pragma unroll
    for (int g = 0; g < 4; ++g){
      int col = g*128 + w*16 + r;
      #pragma unroll
      for (int q = 0; q < 4; ++q){
        const float* p = base + col*128 + q*32 + gq*8;
        f32x4 x0 = *(const f32x4*)p;
        f32x4 x1 = *(const f32x4*)(p + 4);
        us8 tt;
        tt[0]=f2bf(x0[0]); tt[1]=f2bf(x0[1]); tt[2]=f2bf(x0[2]); tt[3]=f2bf(x0[3]);
        tt[4]=f2bf(x1[0]); tt[5]=f2bf(x1[1]); tt[6]=f2bf(x1[2]); tt[7]=f2bf(x1[3]);
        WB[m][g][q] = tt;
      }
    }
  }

  float c0s[2][4], c1s[2][4];
  #pragma unroll
  for (int rt = 0; rt < 2; ++rt)
    #pragma unroll
    for (int j = 0; j < 4; ++j){ c0s[rt][j] = 0.f; c1s[rt][j] = 0.f; }

  __syncthreads();

  // ---------------- time loop ----------------
  for (int t = 0; t < NSTEP; ++t){
    const int pb = t & 1, nb = pb ^ 1;
    const unsigned short* A0r = S.A0[pb];
    unsigned short*       A0w = S.A0[nb];
    const unsigned short* A1r = S.A1[pb];
    unsigned short*       A1w = S.A1[nb];

    // ---- layer 0: gates = x-MFMA + h0 @ Whh0^T ; in-register activations ----
    #pragma unroll
    for (int rt = 0; rt < 2; ++rt){
      const int rbase = rt * 16;
      f32x4 acc[4];
      us8 ax = *(const us8*)&S.Ax[pb][rbase + r][gq*8];
      #pragma unroll
      for (int g = 0; g < 4; ++g){
        us8 bx = *(const us8*)&S.xw[(g*128 + w*16 + r)*8];
        f32x4 z = {0.f,0.f,0.f,0.f};
        acc[g] = MFMA(ax, bx, z);
      }
      #pragma unroll
      for (int q = 0; q < 4; ++q){
        us8 a = *(const us8*)&A0r[(rbase + r)*A_STR + q*32 + gq*8];
        #pragma unroll
        for (int g = 0; g < 4; ++g) acc[g] = MFMA(a, WB[0][g][q], acc[g]);
      }
      #pragma unroll
      for (int j = 0; j < 4; ++j){
        float c = fmaf(sigm(acc[1][j]), c0s[rt][j], sigm(acc[0][j]) * tanh_(acc[2][j]));
        c0s[rt][j] = c;
        float h = sigm(acc[3][j]) * tanh_(c);
        A0w[(rbase + gq*4 + j)*A_STR + w*16 + r] = f2bf(h);
      }
    }
    __syncthreads();   // B1: new h0 visible

    // issue next-step scalar loads early (hide under layer-1 MFMAs)
    float stv = 0.f; int sto = -1;
    if (t + 1 < NSTEP && tid < 160){
      int srow, sch, tau;
      if (tid < 32){ srow = tid; sch = 0; tau = t + 1; }
      else { int k = tid - 32; srow = k >> 2; sch = 1 + (k & 3); tau = t + 2; }
      const float* p = (tau < 96) ? (hist + ((b*96 + tau)*320 + n0 + srow)*5)
                                  : (fut  + ((b*24 + (tau - 96))*320 + n0 + srow)*5);
      stv = p[sch];
      sto = nb*NROW*32 + srow*32 + sch;
    }

    // ---- layer 1: gates = b1 + h0new @ Wih1^T + h1 @ Whh1^T ----
    float b1g[4];
    #pragma unroll
    for (int g = 0; g < 4; ++g) b1g[g] = S.b1[g*128 + w*16 + r];

    #pragma unroll
    for (int rt = 0; rt < 2; ++rt){
      const int rbase = rt * 16;
      f32x4 acc[4];
      #pragma unroll
      for (int g = 0; g < 4; ++g){ f32x4 iv = {b1g[g],b1g[g],b1g[g],b1g[g]}; acc[g] = iv; }
      #pragma unroll
      for (int q = 0; q < 4; ++q){
        us8 a = *(const us8*)&A0w[(rbase + r)*A_STR + q*32 + gq*8];
        #pragma unroll
        for (int g = 0; g < 4; ++g) acc[g] = MFMA(a, WB[1][g][q], acc[g]);
      }
      #pragma unroll
      for (int q = 0; q < 4; ++q){
        us8 a = *(const us8*)&A1r[(rbase + r)*A_STR + q*32 + gq*8];
        #pragma unroll
        for (int g = 0; g < 4; ++g) acc[g] = MFMA(a, WB[2][g][q], acc[g]);
      }
      #pragma unroll
      for (int j = 0; j < 4; ++j){
        float c = fmaf(sigm(acc[1][j]), c1s[rt][j], sigm(acc[0][j]) * tanh_(acc[2][j]));
        c1s[rt][j] = c;
        float h = sigm(acc[3][j]) * tanh_(c);
        A1w[(rbase + gq*4 + j)*A_STR + w*16 + r] = f2bf(h);
      }
    }
    if (sto >= 0) ((unsigned short*)&S.Ax[0][0][0])[sto] = f2bf(stv);
    __syncthreads();   // B2: new h1 + next-step Ax visible

    // ---- head: only last 24 steps ----
    if (t >= 95){
      const int rown = tid >> 4, cg = tid & 15;
      us8 hv = *(const us8*)&A1w[rown*A_STR + cg*8];
      f32x4 wA0 = *(const f32x4*)&S.Wh2f[cg*8];
      f32x4 wA1 = *(const f32x4*)&S.Wh2f[cg*8 + 4];
      f32x4 wB0 = *(const f32x4*)&S.Wh2f[128 + cg*8];
      f32x4 wB1 = *(const f32x4*)&S.Wh2f[128 + cg*8 + 4];
      float pm = 0.f, ps = 0.f;
      #pragma unroll
      for (int k = 0; k < 4; ++k){
        float h0v = bf2f(hv[k]);     h0v = h0v > 0.f ? h0v : 0.f;
        float h1v = bf2f(hv[4 + k]); h1v = h1v > 0.f ? h1v : 0.f;
        pm = fmaf(h0v, wA0[k], pm);  pm = fmaf(h1v, wA1[k], pm);
        ps = fmaf(h0v, wB0[k], ps);  ps = fmaf(h1v, wB1[k], ps);
      }
      S.red[rown][cg][0] = pm; S.red[rown][cg][1] = ps;
      __syncthreads(); // B3 (uniform: t is uniform)
      if (tid < 64){
        int row = tid >> 1, o = tid & 1;
        float s = S.bh_s[o];
        #pragma unroll
        for (int k = 0; k < 16; ++k) s += S.red[row][k][o];
        if (o) s = (s > 15.f) ? s : __logf(1.0f + __expf(s));
        out[((b*24 + (t - 95))*320 + (n0 + row))*2 + o] = s;
      }
    }
  }
}

extern "C" void kernel_launch(void* const* d_in, const int* in_sizes, int n_in,
                              void* d_out, int out_size, void* d_ws, size_t ws_size,
                              hipStream_t stream) {
  const float* hist = (const float*)d_in[0];
  const float* fut  = (const float*)d_in[1];
  const float* We   = (const float*)d_in[2];
  const float* be   = (const float*)d_in[3];
  const float* Wih0 = (const float*)d_in[4];
  const float* Whh0 = (const float*)d_in[5];
  const float* bih0 = (const float*)d_in[6];
  const float* bhh0 = (const float*)d_in[7];
  const float* Wih1 = (const float*)d_in[8];
  const float* Whh1 = (const float*)d_in[9];
  const float* bih1 = (const float*)d_in[10];
  const float* bhh1 = (const float*)d_in[11];
  const float* Wh   = (const float*)d_in[12];
  const float* bh   = (const float*)d_in[13];
  float* out = (float*)d_out;

  deepar_kernel<<<dim3(160), dim3(512), 0, stream>>>(
      hist, fut, We, be, Wih0, Whh0, bih0, bhh0,
      Wih1, Whh1, bih1, bhh1, Wh, bh, out);
}